// Round 14
// baseline (98.134 us; speedup 1.0000x reference)
//
#include <hip/hip_runtime.h>

#define CDIM 256
#define SCALING 0.17677669529663687f  // 32^-0.5

typedef _Float16 f16;
typedef f16 f16x4 __attribute__((ext_vector_type(4)));
typedef f16 f16x8 __attribute__((ext_vector_type(8)));
typedef float f32x4 __attribute__((ext_vector_type(4)));

// Standard gfx950 16x16x32 f16 fragment mapping (m89-verified D; bench-verified A/B):
//   A[m][k]: lane l, reg j  ->  m = l&15,          k = 8*(l>>4) + j   (k contiguous)
//   B[k][n]: lane l, reg j  ->  k = 8*(l>>4) + j,  n = l&15           (k contiguous)
//   D[m][n]: lane l, reg r  ->  m = 4*(l>>4) + r,  n = l&15
#define MFMA(a, b, c) __builtin_amdgcn_mfma_f32_16x16x32_f16(a, b, c, 0, 0, 0)

__device__ __forceinline__ unsigned pack2(float a, float b) {
  union { f16 h[2]; unsigned u; } r;
  r.h[0] = (f16)a;
  r.h[1] = (f16)b;
  return r.u;
}

// ---------------- K0: W2_hd = scaling * wk_hd^T @ wq_hd ; b2 ; wv -> f16 ----------------
// grid (32 ci-octs, 8 hd) x 256 (t = cx)
__global__ __launch_bounds__(256) void k_prep_w2(const float* __restrict__ wq,
                                                 const float* __restrict__ bq,
                                                 const float* __restrict__ wk,
                                                 const float* __restrict__ wv,
                                                 f16* __restrict__ W2h,
                                                 float* __restrict__ b2,
                                                 f16* __restrict__ wvh) {
  __shared__ float wk_s[32][8];
  const int t = threadIdx.x, ciO = blockIdx.x, hd = blockIdx.y;
  {
    int j = t >> 3, c8 = t & 7;
    wk_s[j][c8] = wk[(hd * 32 + j) * CDIM + ciO * 8 + c8];
    int idx = (hd * 32 + j) * CDIM + ciO * 8 + c8;
    wvh[idx] = (f16)wv[idx];
  }
  float wq_r[32];
#pragma unroll
  for (int j = 0; j < 32; ++j) wq_r[j] = wq[(hd * 32 + j) * CDIM + t];
  __syncthreads();
  for (int c8 = 0; c8 < 8; ++c8) {
    float acc = 0.f;
#pragma unroll
    for (int j = 0; j < 32; ++j) acc = fmaf(wq_r[j], wk_s[j][c8], acc);
    W2h[(size_t)(hd * CDIM + ciO * 8 + c8) * CDIM + t] = (f16)(acc * SCALING);
  }
  if (t < 8) {
    float a = 0.f;
    for (int j = 0; j < 32; ++j) a = fmaf(wk_s[j][t], bq[hd * 32 + j], a);
    b2[hd * CDIM + ciO * 8 + t] = a * SCALING;
  }
}

// ---------------- K0b: xT[b][pix][cx] = f16(x[b][cx][pix]) ; gate ----------------
// grid (32 pix-32-tiles, nb) x 256. Coalesced read (pix-contig) + coalesced write
// (cx-contig rows). Gate sigma(wg.x+bg) folded in (reads every x element anyway).
__global__ __launch_bounds__(256) void k_xt(const float* __restrict__ x,
                                            const float* __restrict__ wg,
                                            const float* __restrict__ bg,
                                            f16* __restrict__ xT,
                                            float* __restrict__ gw, int b0) {
  __shared__ f16 tile[32][260];  // [pix][256cx +4 pad] 16640 B
  const int t = threadIdx.x;
  const int pT = blockIdx.x, bz = blockIdx.y;
  const int bb = b0 + bz;
  const float* xb = x + (size_t)bb * (CDIM * 1024) + pT * 32;
#pragma unroll
  for (int it = 0; it < 8; ++it) {
    int e = it * 256 + t, p4 = e & 7, cx = e >> 3;
    float4 v = *(const float4*)(xb + (size_t)cx * 1024 + p4 * 4);
    tile[p4 * 4 + 0][cx] = (f16)v.x;
    tile[p4 * 4 + 1][cx] = (f16)v.y;
    tile[p4 * 4 + 2][cx] = (f16)v.z;
    tile[p4 * 4 + 3][cx] = (f16)v.w;
  }
  __syncthreads();
  f16* xTb = xT + (size_t)bz * (1024 * CDIM) + pT * 32 * CDIM;
#pragma unroll
  for (int it = 0; it < 4; ++it) {
    int e = it * 256 + t, cxo = e & 31, pix = e >> 5;
    *(f16x8*)(xTb + pix * CDIM + cxo * 8) = *(const f16x8*)(&tile[pix][cxo * 8]);
  }
  if (t < 32) {
    float a = 0.f;
    for (int cx = 0; cx < CDIM; ++cx) a = fmaf((float)tile[t][cx], wg[cx], a);
    gw[bz * 1024 + pT * 32 + t] = 1.f / (1.f + __expf(-(a + bg[0])));
  }
}

// ---------------- K1: qk[b][pix][hd][ci] = W2_hd @ xT^T + b2 ----------------
// grid (16 pix-64-slices, 8 hd, nb) x 256. M=256ci, N=64pix, K=256cx.
// ZERO LDS, ZERO barriers: A rows direct from W2h, B rows direct from xT (both
// k-contiguous 16B/lane, L2-hot slices).
__global__ __launch_bounds__(256, 2) void k_qkw2(const f16* __restrict__ xT,
                                                 const f16* __restrict__ W2h,
                                                 const float* __restrict__ b2,
                                                 f16* __restrict__ qk, int b0) {
  const int t = threadIdx.x;
  const int p16 = blockIdx.x, hd = blockIdx.y, bz = blockIdx.z;
  const int lane = t & 63, wid = t >> 6, l15 = lane & 15, h4 = lane >> 4;
  const f16* Whd = W2h + (size_t)hd * CDIM * CDIM;
  const f16* xTb = xT + (size_t)bz * (1024 * CDIM) + (size_t)(p16 * 64) * CDIM;
  f32x4 acc[4][4] = {};

  for (int kb = 0; kb < 8; ++kb) {
    f16x8 a[4], bf[4];
#pragma unroll
    for (int mt = 0; mt < 4; ++mt)  // A[m=ci][k=cx]
      a[mt] = *(const f16x8*)(Whd + (size_t)(wid * 64 + mt * 16 + l15) * CDIM + kb * 32 +
                              h4 * 8);
#pragma unroll
    for (int nt = 0; nt < 4; ++nt)  // B[k=cx][n=pix] from xT[pix][cx]
      bf[nt] = *(const f16x8*)(xTb + (size_t)(nt * 16 + l15) * CDIM + kb * 32 + h4 * 8);
#pragma unroll
    for (int mt = 0; mt < 4; ++mt)
#pragma unroll
      for (int nt = 0; nt < 4; ++nt) acc[mt][nt] = MFMA(a[mt], bf[nt], acc[mt][nt]);
  }
#pragma unroll
  for (int mt = 0; mt < 4; ++mt) {
    int ci0 = wid * 64 + mt * 16 + h4 * 4;
    float4 bvv = *(const float4*)(b2 + hd * CDIM + ci0);
#pragma unroll
    for (int nt = 0; nt < 4; ++nt) {
      int pix = p16 * 64 + nt * 16 + l15;
      union { f16 h[4]; unsigned long long u; } P;
      P.h[0] = (f16)(acc[mt][nt][0] + bvv.x);
      P.h[1] = (f16)(acc[mt][nt][1] + bvv.y);
      P.h[2] = (f16)(acc[mt][nt][2] + bvv.z);
      P.h[3] = (f16)(acc[mt][nt][3] + bvv.w);
      *(unsigned long long*)(qk + ((size_t)(bz * 1024 + pix) * 8 + hd) * CDIM + ci0) = P.u;
    }
  }
}

// ---------------- K2: fused local attention (R12 form — measured best) ----------------
// block (h, w4, b): 4 query pixels, wave w owns pixel w. LDS = 40960 B, 4 blk/CU.
__global__ __launch_bounds__(256, 4) void k_attn(const float* __restrict__ feat,
                                                 const f16* __restrict__ qk,
                                                 f16* __restrict__ fa, int b0) {
  __shared__ __align__(16) f16 cip[4 * 4608];    // 36864 B [px][ci][18]
  __shared__ __align__(16) f16 attn_l[4 * 512];  //  4096 B [w][32p][16hd]
  const int t = threadIdx.x;
  const int h = blockIdx.x, w4 = blockIdx.y, bz = blockIdx.z;
  const int bb = b0 + bz;
  const int lane = t & 63, w = t >> 6, l15 = lane & 15, h4 = lane >> 4;
  const int pixb = h * 32 + w4 * 4;

  const float* fb = feat + (size_t)bb * (CDIM * 16384) + (h * 4) * 128 + w4 * 16;
  float4 fv[8];
#pragma unroll
  for (int it = 0; it < 8; ++it) {
    int e = it * 256 + t, px = e & 3, r = (e >> 2) & 3, ci = e >> 4;
    fv[it] = *(const float4*)(fb + (size_t)ci * 16384 + r * 128 + px * 4);
  }
  const f16* qkg = qk + ((size_t)(bz * 1024 + pixb + w) * 8 + (l15 & 7)) * CDIM;
  f16x8 apre[8];
#pragma unroll
  for (int kb = 0; kb < 8; ++kb) apre[kb] = *(const f16x8*)(qkg + kb * 32 + h4 * 8);
  {
    f16x8 z = {};
    *(f16x8*)(attn_l + t * 8) = z;
  }
#pragma unroll
  for (int it = 0; it < 4; ++it) {
    int e = it * 256 + t, px = e >> 8, ci = e & 255;
    *(unsigned*)(cip + px * 4608 + ci * 18 + 16) = 0;
  }
#pragma unroll
  for (int it = 0; it < 8; ++it) {
    int e = it * 256 + t, px = e & 3, r = (e >> 2) & 3, ci = e >> 4;
    uint2 pk;
    pk.x = pack2(fv[it].x, fv[it].y);
    pk.y = pack2(fv[it].z, fv[it].w);
    *(uint2*)(cip + px * 4608 + ci * 18 + r * 4) = pk;
  }
#pragma unroll
  for (int it = 8; it < 16; ++it) {
    int e = it * 256 + t, px = e & 3, r = (e >> 2) & 3, ci = e >> 4;
    float4 v = *(const float4*)(fb + (size_t)ci * 16384 + r * 128 + px * 4);
    uint2 pk;
    pk.x = pack2(v.x, v.y);
    pk.y = pack2(v.z, v.w);
    *(uint2*)(cip + px * 4608 + ci * 18 + r * 4) = pk;
  }
  __syncthreads();

  const f16* cw = cip + w * 4608;
  f32x4 acc = {};
#pragma unroll
  for (int kb = 0; kb < 8; ++kb) {
    f16x8 bf;
#pragma unroll
    for (int j = 0; j < 8; ++j) bf[j] = cw[(kb * 32 + h4 * 8 + j) * 18 + l15];
    acc = MFMA(apre[kb], bf, acc);
  }
  float at[4];
#pragma unroll
  for (int r = 0; r < 4; ++r) {
    float m = acc[r];
    m = fmaxf(m, __shfl_xor(m, 1, 64));
    m = fmaxf(m, __shfl_xor(m, 2, 64));
    m = fmaxf(m, __shfl_xor(m, 4, 64));
    m = fmaxf(m, __shfl_xor(m, 8, 64));
    float e = __expf(acc[r] - m);
    float s = e;
    s += __shfl_xor(s, 1, 64);
    s += __shfl_xor(s, 2, 64);
    s += __shfl_xor(s, 4, 64);
    s += __shfl_xor(s, 8, 64);
    at[r] = e / s;
  }
  if (h4 < 2) {
#pragma unroll
    for (int r = 0; r < 4; ++r) attn_l[w * 512 + l15 * 16 + h4 * 4 + r] = (f16)at[r];
  }
  f16x8 b5;
#pragma unroll
  for (int j = 0; j < 8; ++j) b5[j] = attn_l[w * 512 + (h4 * 8 + j) * 16 + l15];
  const f32x4 zero = {};
#pragma unroll
  for (int nt = 0; nt < 16; ++nt) {
    const unsigned* ap = (const unsigned*)(cw + (nt * 16 + l15) * 18 + h4 * 8);
    union { unsigned u[4]; f16x8 h; } A;
    A.u[0] = ap[0]; A.u[1] = ap[1]; A.u[2] = ap[2]; A.u[3] = ap[3];
    f32x4 d = MFMA(A.h, b5, zero);
    if (l15 < 8) {
      union { f16 h[4]; unsigned long long u; } P;
      P.h[0] = (f16)d[0]; P.h[1] = (f16)d[1]; P.h[2] = (f16)d[2]; P.h[3] = (f16)d[3];
      *(unsigned long long*)(fa + ((size_t)(bz * 8 + l15) * 1024 + pixb + w) * CDIM +
                             nt * 16 + h4 * 4) = P.u;
    }
  }
}

// ---------------- K3: out[c][pix] = (wv @ fa + bv) * gw (R12 form) ----------------
__global__ __launch_bounds__(256) void k_out(const f16* __restrict__ fa,
                                             const f16* __restrict__ wvh,
                                             const float* __restrict__ bv,
                                             const float* __restrict__ gw,
                                             float* __restrict__ out, int b0) {
  __shared__ __align__(16) f16 wv_l[32 * 264];  // [c][256ci +8pad] 16896 B
  const int t = threadIdx.x;
  const int p16 = blockIdx.x, hd = blockIdx.y, bz = blockIdx.z;
  const int bb = b0 + bz;
  const int lane = t & 63, wid = t >> 6, l15 = lane & 15, h4 = lane >> 4;

  const f16* fap = fa + ((size_t)(bz * 8 + hd) * 1024 + p16 * 64 + wid * 16 + l15) * CDIM +
                   h4 * 8;
  f16x8 apre[8];
#pragma unroll
  for (int kb = 0; kb < 8; ++kb) apre[kb] = *(const f16x8*)(fap + kb * 32);
  int pix0 = p16 * 64 + wid * 16 + h4 * 4;
  float4 g = *(const float4*)(gw + bz * 1024 + pix0);

#pragma unroll
  for (int it = 0; it < 4; ++it) {
    int e = it * 256 + t, c = e >> 5, ch = e & 31;
    *(f16x8*)(wv_l + c * 264 + ch * 8) =
        *(const f16x8*)(wvh + (size_t)(hd * 32 + c) * CDIM + ch * 8);
  }
  __syncthreads();
  f32x4 acc[2] = {};
#pragma unroll
  for (int kb = 0; kb < 8; ++kb) {
#pragma unroll
    for (int nt = 0; nt < 2; ++nt) {
      f16x8 b = *(const f16x8*)(wv_l + (nt * 16 + l15) * 264 + kb * 32 + h4 * 8);
      acc[nt] = MFMA(apre[kb], b, acc[nt]);
    }
  }
#pragma unroll
  for (int nt = 0; nt < 2; ++nt) {
    int c = hd * 32 + nt * 16 + l15;
    float bvc = bv[c];
    float4 o;
    o.x = (acc[nt][0] + bvc) * g.x;
    o.y = (acc[nt][1] + bvc) * g.y;
    o.z = (acc[nt][2] + bvc) * g.z;
    o.w = (acc[nt][3] + bvc) * g.w;
    *(float4*)(out + (size_t)(bb * CDIM + c) * 1024 + pix0) = o;
  }
}

// ---------------- launcher ----------------
extern "C" void kernel_launch(void* const* d_in, const int* in_sizes, int n_in,
                              void* d_out, int out_size, void* d_ws, size_t ws_size,
                              hipStream_t stream) {
  const float* x = (const float*)d_in[0];
  const float* feat = (const float*)d_in[1];
  const float* wq = (const float*)d_in[2];
  const float* bq = (const float*)d_in[3];
  const float* wk = (const float*)d_in[4];
  // d_in[5] = bk: constant over grid positions -> cancels in softmax, unused
  const float* wv = (const float*)d_in[6];
  const float* bv = (const float*)d_in[7];
  const float* wg = (const float*)d_in[8];
  const float* bg = (const float*)d_in[9];
  float* out = (float*)d_out;

  char* ws = (char*)d_ws;
  f16* W2h = (f16*)ws;                 // 1,048,576 B
  float* b2 = (float*)(ws + 1048576);  //     8,192 B
  f16* wvh = (f16*)(ws + 1056768);     //   131,072 B
  char* dyn = ws + 1187840;

  k_prep_w2<<<dim3(32, 8), 256, 0, stream>>>(wq, bq, wk, wv, W2h, b2, wvh);

  const size_t XT = 4194304, QK = 4194304, FA = 4194304, GW = 4096;  // per batch (XT total 8b)
  if (ws_size >= 1187840 + 8 * (XT / 8 * 0 + QK + FA + GW) + 8 * 524288 + 4194304) {
    // layout: xT (4 MB, all batches) | qk (32 MB) | fa (32 MB) | gw (32 KB)
    f16* xT = (f16*)dyn;
    f16* qkp = (f16*)(dyn + 4194304);
    f16* fap = (f16*)(dyn + 4194304 + 8 * QK);
    float* gwp = (float*)(dyn + 4194304 + 8 * QK + 8 * FA);
    k_xt<<<dim3(32, 8), 256, 0, stream>>>(x, wg, bg, xT, gwp, 0);
    k_qkw2<<<dim3(16, 8, 8), 256, 0, stream>>>(xT, W2h, b2, qkp, 0);
    k_attn<<<dim3(32, 8, 8), 256, 0, stream>>>(feat, qkp, fap, 0);
    k_out<<<dim3(16, 8, 8), 256, 0, stream>>>(fap, wvh, bv, gwp, out, 0);
  } else {  // per-batch fallback (~9.1 MB workspace)
    f16* xT = (f16*)dyn;
    f16* qkp = (f16*)(dyn + 524288);
    f16* fap = (f16*)(dyn + 524288 + QK);
    float* gwp = (float*)(dyn + 524288 + QK + FA);
    for (int b = 0; b < 8; ++b) {
      k_xt<<<dim3(32, 1), 256, 0, stream>>>(x, wg, bg, xT, gwp, b);
      k_qkw2<<<dim3(16, 8, 1), 256, 0, stream>>>(xT, W2h, b2, qkp, b);
      k_attn<<<dim3(32, 8, 1), 256, 0, stream>>>(feat, qkp, fap, b);
      k_out<<<dim3(16, 8, 1), 256, 0, stream>>>(fap, wvh, bv, gwp, out, b);
    }
  }
}

// Round 15
// 79.108 us; speedup vs baseline: 1.2405x; 1.2405x over previous
//
#include <hip/hip_runtime.h>

#define CDIM 256
#define SCALING 0.17677669529663687f  // 32^-0.5

typedef _Float16 f16;
typedef f16 f16x4 __attribute__((ext_vector_type(4)));
typedef f16 f16x8 __attribute__((ext_vector_type(8)));
typedef float f32x4 __attribute__((ext_vector_type(4)));

// Standard gfx950 16x16x32 f16 fragment mapping (m89-verified D; bench-verified A/B):
//   A[m][k]: lane l, reg j  ->  m = l&15,          k = 8*(l>>4) + j   (k contiguous)
//   B[k][n]: lane l, reg j  ->  k = 8*(l>>4) + j,  n = l&15           (k contiguous)
//   D[m][n]: lane l, reg r  ->  m = 4*(l>>4) + r,  n = l&15
#define MFMA(a, b, c) __builtin_amdgcn_mfma_f32_16x16x32_f16(a, b, c, 0, 0, 0)

__device__ __forceinline__ unsigned pack2(float a, float b) {
  union { f16 h[2]; unsigned u; } r;
  r.h[0] = (f16)a;
  r.h[1] = (f16)b;
  return r.u;
}

// ---------------- K0: W2_hd = scaling * wk_hd^T @ wq_hd ; b2 ; wv -> f16 ----------------
// grid (32 ci-octs, 8 hd) x 256 (t = cx)
__global__ __launch_bounds__(256) void k_prep_w2(const float* __restrict__ wq,
                                                 const float* __restrict__ bq,
                                                 const float* __restrict__ wk,
                                                 const float* __restrict__ wv,
                                                 f16* __restrict__ W2h,
                                                 float* __restrict__ b2,
                                                 f16* __restrict__ wvh) {
  __shared__ float wk_s[32][8];
  const int t = threadIdx.x, ciO = blockIdx.x, hd = blockIdx.y;
  {
    int j = t >> 3, c8 = t & 7;
    wk_s[j][c8] = wk[(hd * 32 + j) * CDIM + ciO * 8 + c8];
    int idx = (hd * 32 + j) * CDIM + ciO * 8 + c8;
    wvh[idx] = (f16)wv[idx];
  }
  float wq_r[32];
#pragma unroll
  for (int j = 0; j < 32; ++j) wq_r[j] = wq[(hd * 32 + j) * CDIM + t];
  __syncthreads();
  for (int c8 = 0; c8 < 8; ++c8) {
    float acc = 0.f;
#pragma unroll
    for (int j = 0; j < 32; ++j) acc = fmaf(wq_r[j], wk_s[j][c8], acc);
    W2h[(size_t)(hd * CDIM + ciO * 8 + c8) * CDIM + t] = (f16)(acc * SCALING);
  }
  if (t < 8) {
    float a = 0.f;
    for (int j = 0; j < 32; ++j) a = fmaf(wk_s[j][t], bq[hd * 32 + j], a);
    b2[hd * CDIM + ciO * 8 + t] = a * SCALING;
  }
}

// ---------------- K1: qk[b][pix][hd][ci] = W2_hd @ x + b2 ; gate ----------------
// grid (16 pix-64-slices, 8 hd, nb) x 256. M=256ci, N=64pix, K=256cx.
// R8 form — measured best across R8-R14 (N=128 spilled; zero-LDS serialized).
__global__ __launch_bounds__(256, 2) void k_qkw2(const float* __restrict__ x,
                                                 const f16* __restrict__ W2h,
                                                 const float* __restrict__ b2,
                                                 const float* __restrict__ wg,
                                                 const float* __restrict__ bg,
                                                 f16* __restrict__ qk,
                                                 float* __restrict__ gw, int b0) {
  __shared__ __align__(16) f16 A_l[256 * 40];  // [ci][32cx + 8 pad]  20480 B
  __shared__ __align__(16) f16 B_l[64 * 40];   // [pix][32cx + 8 pad]  5120 B
  const int t = threadIdx.x;
  const int p16 = blockIdx.x, hd = blockIdx.y, bz = blockIdx.z;
  const int bb = b0 + bz;
  const int lane = t & 63, wid = t >> 6, l15 = lane & 15, h4 = lane >> 4;
  f32x4 acc[4][4] = {};
  float gacc = 0.f;

  for (int kb = 0; kb < 8; ++kb) {
    __syncthreads();
#pragma unroll
    for (int it = 0; it < 4; ++it) {
      int e = it * 256 + t, ci = e >> 2, q = e & 3;
      *(f16x8*)(A_l + ci * 40 + q * 8) =
          *(const f16x8*)(W2h + (size_t)(hd * CDIM + ci) * CDIM + kb * 32 + q * 8);
    }
#pragma unroll
    for (int it = 0; it < 2; ++it) {
      int e = it * 256 + t, cx = e >> 4, p4 = e & 15;
      float4 v = *(const float4*)(x + (size_t)(bb * CDIM + kb * 32 + cx) * 1024 +
                                  p16 * 64 + p4 * 4);
      B_l[(p4 * 4 + 0) * 40 + cx] = (f16)v.x;
      B_l[(p4 * 4 + 1) * 40 + cx] = (f16)v.y;
      B_l[(p4 * 4 + 2) * 40 + cx] = (f16)v.z;
      B_l[(p4 * 4 + 3) * 40 + cx] = (f16)v.w;
    }
    __syncthreads();
    if (hd == 0 && wid == 3) {
#pragma unroll
      for (int cx = 0; cx < 32; ++cx)
        gacc = fmaf(wg[kb * 32 + cx], (float)B_l[lane * 40 + cx], gacc);
    }
    f16x8 a[4], bf[4];
#pragma unroll
    for (int mt = 0; mt < 4; ++mt)
      a[mt] = *(const f16x8*)(A_l + (wid * 64 + mt * 16 + l15) * 40 + h4 * 8);
#pragma unroll
    for (int nt = 0; nt < 4; ++nt)
      bf[nt] = *(const f16x8*)(B_l + (nt * 16 + l15) * 40 + h4 * 8);
#pragma unroll
    for (int mt = 0; mt < 4; ++mt)
#pragma unroll
      for (int nt = 0; nt < 4; ++nt) acc[mt][nt] = MFMA(a[mt], bf[nt], acc[mt][nt]);
  }
#pragma unroll
  for (int mt = 0; mt < 4; ++mt) {
    int ci0 = wid * 64 + mt * 16 + h4 * 4;
    float4 bvv = *(const float4*)(b2 + hd * CDIM + ci0);
#pragma unroll
    for (int nt = 0; nt < 4; ++nt) {
      int pix = p16 * 64 + nt * 16 + l15;
      union { f16 h[4]; unsigned long long u; } P;
      P.h[0] = (f16)(acc[mt][nt][0] + bvv.x);
      P.h[1] = (f16)(acc[mt][nt][1] + bvv.y);
      P.h[2] = (f16)(acc[mt][nt][2] + bvv.z);
      P.h[3] = (f16)(acc[mt][nt][3] + bvv.w);
      *(unsigned long long*)(qk + ((size_t)(bz * 1024 + pix) * 8 + hd) * CDIM + ci0) = P.u;
    }
  }
  if (hd == 0 && wid == 3)
    gw[bz * 1024 + p16 * 64 + lane] = 1.f / (1.f + __expf(-(gacc + bg[0])));
}

// ---------------- K2: fused local attention (single layout, 1 barrier, 4 blk/CU) ------
// block (h, w4, b): 4 query pixels, wave w owns pixel w. LDS = 40960 B exactly.
// cip[px][256ci][18] (16 p + 2 ZEROED pad; stride-18 -> conflict-free P3/P5 reads)
__global__ __launch_bounds__(256, 4) void k_attn(const float* __restrict__ feat,
                                                 const f16* __restrict__ qk,
                                                 f16* __restrict__ fa, int b0) {
  __shared__ __align__(16) f16 cip[4 * 4608];    // 36864 B [px][ci][18]
  __shared__ __align__(16) f16 attn_l[4 * 512];  //  4096 B [w][32p][16hd]
  const int t = threadIdx.x;
  const int h = blockIdx.x, w4 = blockIdx.y, bz = blockIdx.z;
  const int bb = b0 + bz;
  const int lane = t & 63, w = t >> 6, l15 = lane & 15, h4 = lane >> 4;
  const int pixb = h * 32 + w4 * 4;

  // ---- issue feat loads first (8 in flight; barrier-critical path) ----
  const float* fb = feat + (size_t)bb * (CDIM * 16384) + (h * 4) * 128 + w4 * 16;
  float4 fv[8];
#pragma unroll
  for (int it = 0; it < 8; ++it) {
    int e = it * 256 + t, px = e & 3, r = (e >> 2) & 3, ci = e >> 4;
    fv[it] = *(const float4*)(fb + (size_t)ci * 16384 + r * 128 + px * 4);
  }
  // ---- qk prefetch (needed only after barrier) + zero-fills under load latency ----
  const f16* qkg = qk + ((size_t)(bz * 1024 + pixb + w) * 8 + (l15 & 7)) * CDIM;
  f16x8 apre[8];
#pragma unroll
  for (int kb = 0; kb < 8; ++kb) apre[kb] = *(const f16x8*)(qkg + kb * 32 + h4 * 8);
  {  // zero attn_l: p>=16 rows = K-padding zeros; hd>=8 cols = zeros (discarded)
    f16x8 z = {};
    *(f16x8*)(attn_l + t * 8) = z;
  }
  // zero every row's 2-f16 pad (P5 A k=16,17 junk x zero attn rows must be finite)
#pragma unroll
  for (int it = 0; it < 4; ++it) {
    int e = it * 256 + t, px = e >> 8, ci = e & 255;
    *(unsigned*)(cip + px * 4608 + ci * 18 + 16) = 0;
  }
  // ---- write first half, streaming; then second half load+write ----
#pragma unroll
  for (int it = 0; it < 8; ++it) {
    int e = it * 256 + t, px = e & 3, r = (e >> 2) & 3, ci = e >> 4;
    uint2 pk;
    pk.x = pack2(fv[it].x, fv[it].y);
    pk.y = pack2(fv[it].z, fv[it].w);
    *(uint2*)(cip + px * 4608 + ci * 18 + r * 4) = pk;
  }
#pragma unroll
  for (int it = 8; it < 16; ++it) {
    int e = it * 256 + t, px = e & 3, r = (e >> 2) & 3, ci = e >> 4;
    float4 v = *(const float4*)(fb + (size_t)ci * 16384 + r * 128 + px * 4);
    uint2 pk;
    pk.x = pack2(v.x, v.y);
    pk.y = pack2(v.z, v.w);
    *(uint2*)(cip + px * 4608 + ci * 18 + r * 4) = pk;
  }
  __syncthreads();

  // ---- P3: logits[hd][p]; A prefetched (rows 8-15 alias 0-7, dupes discarded) ----
  const f16* cw = cip + w * 4608;
  f32x4 acc = {};
#pragma unroll
  for (int kb = 0; kb < 8; ++kb) {
    f16x8 bf;  // B[ci][p]: 8 x u16, conflict-free (stride-18 bank math)
#pragma unroll
    for (int j = 0; j < 8; ++j) bf[j] = cw[(kb * 32 + h4 * 8 + j) * 18 + l15];
    acc = MFMA(apre[kb], bf, acc);
  }
  // ---- softmax over p (= lane&15), hd = 4*h4 + r (h4<2 real, rest dupes) ----
  float at[4];
#pragma unroll
  for (int r = 0; r < 4; ++r) {
    float m = acc[r];
    m = fmaxf(m, __shfl_xor(m, 1, 64));
    m = fmaxf(m, __shfl_xor(m, 2, 64));
    m = fmaxf(m, __shfl_xor(m, 4, 64));
    m = fmaxf(m, __shfl_xor(m, 8, 64));
    float e = __expf(acc[r] - m);
    float s = e;
    s += __shfl_xor(s, 1, 64);
    s += __shfl_xor(s, 2, 64);
    s += __shfl_xor(s, 4, 64);
    s += __shfl_xor(s, 8, 64);
    at[r] = e / s;
  }
  if (h4 < 2) {  // store attn TRANSPOSED: [p][hd]
#pragma unroll
    for (int r = 0; r < 4; ++r) attn_l[w * 512 + l15 * 16 + h4 * 4 + r] = (f16)at[r];
  }
  // ---- P5'': D[m=ci_loc][n=hd] = A(feat)[ci][32p] @ B(attn)[32p][16hd] ----
  f16x8 b5;  // B[k=p][n=hd], loop-invariant (same-wave RAW on attn_l, in-order DS)
#pragma unroll
  for (int j = 0; j < 8; ++j) b5[j] = attn_l[w * 512 + (h4 * 8 + j) * 16 + l15];
  const f32x4 zero = {};
#pragma unroll
  for (int nt = 0; nt < 16; ++nt) {
    const unsigned* ap = (const unsigned*)(cw + (nt * 16 + l15) * 18 + h4 * 8);
    union { unsigned u[4]; f16x8 h; } A;
    A.u[0] = ap[0]; A.u[1] = ap[1]; A.u[2] = ap[2]; A.u[3] = ap[3];
    f32x4 d = MFMA(A.h, b5, zero);
    if (l15 < 8) {  // n = l15 = hd (0..7 real); m = 4*h4 + r -> ci contiguous
      union { f16 h[4]; unsigned long long u; } P;
      P.h[0] = (f16)d[0]; P.h[1] = (f16)d[1]; P.h[2] = (f16)d[2]; P.h[3] = (f16)d[3];
      *(unsigned long long*)(fa + ((size_t)(bz * 8 + l15) * 1024 + pixb + w) * CDIM +
                             nt * 16 + h4 * 4) = P.u;
    }
  }
}

// ---------------- K3: out[c][pix] = (wv @ fa + bv) * gw ----------------
// grid (16 pix-64, 8 hd, nb) x 256. A (fa) direct from global, PREFETCHED.
__global__ __launch_bounds__(256) void k_out(const f16* __restrict__ fa,
                                             const f16* __restrict__ wvh,
                                             const float* __restrict__ bv,
                                             const float* __restrict__ gw,
                                             float* __restrict__ out, int b0) {
  __shared__ __align__(16) f16 wv_l[32 * 264];  // [c][256ci +8pad] 16896 B
  const int t = threadIdx.x;
  const int p16 = blockIdx.x, hd = blockIdx.y, bz = blockIdx.z;
  const int bb = b0 + bz;
  const int lane = t & 63, wid = t >> 6, l15 = lane & 15, h4 = lane >> 4;

  // prefetch all 8 A-fragments + epilogue scalars first (independent of wv staging)
  const f16* fap = fa + ((size_t)(bz * 8 + hd) * 1024 + p16 * 64 + wid * 16 + l15) * CDIM +
                   h4 * 8;
  f16x8 apre[8];
#pragma unroll
  for (int kb = 0; kb < 8; ++kb) apre[kb] = *(const f16x8*)(fap + kb * 32);
  int pix0 = p16 * 64 + wid * 16 + h4 * 4;
  float4 g = *(const float4*)(gw + bz * 1024 + pix0);

#pragma unroll
  for (int it = 0; it < 4; ++it) {
    int e = it * 256 + t, c = e >> 5, ch = e & 31;
    *(f16x8*)(wv_l + c * 264 + ch * 8) =
        *(const f16x8*)(wvh + (size_t)(hd * 32 + c) * CDIM + ch * 8);
  }
  __syncthreads();
  f32x4 acc[2] = {};
#pragma unroll
  for (int kb = 0; kb < 8; ++kb) {
#pragma unroll
    for (int nt = 0; nt < 2; ++nt) {
      f16x8 b = *(const f16x8*)(wv_l + (nt * 16 + l15) * 264 + kb * 32 + h4 * 8);  // B[ci][c]
      acc[nt] = MFMA(apre[kb], b, acc[nt]);
    }
  }
#pragma unroll
  for (int nt = 0; nt < 2; ++nt) {
    int c = hd * 32 + nt * 16 + l15;
    float bvc = bv[c];
    float4 o;
    o.x = (acc[nt][0] + bvc) * g.x;
    o.y = (acc[nt][1] + bvc) * g.y;
    o.z = (acc[nt][2] + bvc) * g.z;
    o.w = (acc[nt][3] + bvc) * g.w;
    *(float4*)(out + (size_t)(bb * CDIM + c) * 1024 + pix0) = o;
  }
}

// ---------------- launcher ----------------
extern "C" void kernel_launch(void* const* d_in, const int* in_sizes, int n_in,
                              void* d_out, int out_size, void* d_ws, size_t ws_size,
                              hipStream_t stream) {
  const float* x = (const float*)d_in[0];
  const float* feat = (const float*)d_in[1];
  const float* wq = (const float*)d_in[2];
  const float* bq = (const float*)d_in[3];
  const float* wk = (const float*)d_in[4];
  // d_in[5] = bk: constant over grid positions -> cancels in softmax, unused
  const float* wv = (const float*)d_in[6];
  const float* bv = (const float*)d_in[7];
  const float* wg = (const float*)d_in[8];
  const float* bg = (const float*)d_in[9];
  float* out = (float*)d_out;

  char* ws = (char*)d_ws;
  f16* W2h = (f16*)ws;                 // 1,048,576 B
  float* b2 = (float*)(ws + 1048576);  //     8,192 B
  f16* wvh = (f16*)(ws + 1056768);     //   131,072 B
  char* dyn = ws + 1187840;

  k_prep_w2<<<dim3(32, 8), 256, 0, stream>>>(wq, bq, wk, wv, W2h, b2, wvh);

  const size_t QK = 4194304, FA = 4194304, GW = 4096;  // per batch
  if (ws_size >= 1187840 + 8 * (QK + FA + GW)) {
    f16* qkp = (f16*)dyn;
    f16* fap = (f16*)(dyn + 8 * QK);
    float* gwp = (float*)(dyn + 8 * (QK + FA));
    k_qkw2<<<dim3(16, 8, 8), 256, 0, stream>>>(x, W2h, b2, wg, bg, qkp, gwp, 0);
    k_attn<<<dim3(32, 8, 8), 256, 0, stream>>>(feat, qkp, fap, 0);
    k_out<<<dim3(16, 8, 8), 256, 0, stream>>>(fap, wvh, bv, gwp, out, 0);
  } else {  // per-batch fallback (~9.6 MB workspace)
    f16* qkp = (f16*)dyn;
    f16* fap = (f16*)(dyn + QK);
    float* gwp = (float*)(dyn + QK + FA);
    for (int b = 0; b < 8; ++b) {
      k_qkw2<<<dim3(16, 8, 1), 256, 0, stream>>>(x, W2h, b2, wg, bg, qkp, gwp, b);
      k_attn<<<dim3(32, 8, 1), 256, 0, stream>>>(feat, qkp, fap, b);
      k_out<<<dim3(16, 8, 1), 256, 0, stream>>>(fap, wvh, bv, gwp, out, b);
    }
  }
}